// Round 19
// baseline (232.782 us; speedup 1.0000x reference)
//
#include <hip/hip_runtime.h>
#include <hip/hip_bf16.h>

#define N_TOK 16384
#define DIM 2048
#define KCLS 64
#define JRANGES 32
#define RANGE 512   // N_TOK / JRANGES
#define KC 64       // GEMM K-chunk (bf16, double-buffered)
#define EPS 1e-8f

typedef short bf16x8 __attribute__((ext_vector_type(8)));
typedef unsigned short u16x8 __attribute__((ext_vector_type(8)));
typedef float f32x4 __attribute__((ext_vector_type(4)));

__device__ __forceinline__ unsigned short f2bf(float f) {
    unsigned u = __float_as_uint(f);
    u += 0x7fffu + ((u >> 16) & 1u);
    return (unsigned short)(u >> 16);
}
__device__ __forceinline__ float bf2f(unsigned short s) {
    return __uint_as_float(((unsigned)s) << 16);
}

__device__ __forceinline__ float dpp_sum64(float x) {
    x += __int_as_float(__builtin_amdgcn_update_dpp(0, __float_as_int(x), 0x111, 0xf, 0xf, true));
    x += __int_as_float(__builtin_amdgcn_update_dpp(0, __float_as_int(x), 0x112, 0xf, 0xf, true));
    x += __int_as_float(__builtin_amdgcn_update_dpp(0, __float_as_int(x), 0x114, 0xf, 0xf, true));
    x += __int_as_float(__builtin_amdgcn_update_dpp(0, __float_as_int(x), 0x118, 0xf, 0xf, true));
    x += __int_as_float(__builtin_amdgcn_update_dpp(0, __float_as_int(x), 0x142, 0xf, 0xf, true));
    x += __int_as_float(__builtin_amdgcn_update_dpp(0, __float_as_int(x), 0x143, 0xf, 0xf, true));
    return x;  // valid in lane 63 only
}

// ---------------------------------------------------------------------------
// Kernel 1: prep — cast X to bf16 + exact fp32 token norms.
// Fused: blocks 0..63 normalize the labels chunk (int64/int32 sniff);
// blocks 64..71 zero n2snap (classscan accumulates into it atomically).
__global__ __launch_bounds__(256) void prep_kernel(
    const float* __restrict__ x, unsigned short* __restrict__ xb,
    float* __restrict__ vnorm2, const int* __restrict__ raw,
    int* __restrict__ lab, float* __restrict__ n2snap) {
    int bid = blockIdx.x, tid = threadIdx.x;
    if (bid < 64) {  // label duty (block-uniform branch)
        __shared__ int not64;
        if (tid == 0) not64 = 0;
        __syncthreads();
        int n0 = bid * 256 + tid;
        int lo = raw[2 * n0], hi = raw[2 * n0 + 1];
        if (hi != 0 || lo < 0 || lo >= KCLS) atomicOr(&not64, 1);
        __syncthreads();
        lab[n0] = not64 ? raw[n0] : raw[2 * n0];
    } else if (bid < 72) {
        n2snap[(bid - 64) * 256 + tid] = 0.f;
    }
    int w4 = tid >> 6, lane = tid & 63;
    int n = bid * 4 + w4;
    const float* v = x + (size_t)n * DIM;
    unsigned short* o = xb + (size_t)n * DIM;
    float p = 0.f;
#pragma unroll
    for (int it = 0; it < 8; it++) {
        float4 a = *(const float4*)(v + it * 256 + lane * 4);
        p = fmaf(a.x, a.x, p); p = fmaf(a.y, a.y, p);
        p = fmaf(a.z, a.z, p); p = fmaf(a.w, a.w, p);
        ushort4 h = make_ushort4(f2bf(a.x), f2bf(a.y), f2bf(a.z), f2bf(a.w));
        *(ushort4*)(o + it * 256 + lane * 4) = h;
    }
    p = dpp_sum64(p);
    if (lane == 63) vnorm2[n] = p;
}

// ---------------------------------------------------------------------------
// Kernel 2: classscan v2 — replaces partials + scan (+ spart + a launch gap).
// Block = (class k, dim-slice s of 4); 256 blocks x 256 threads (fixes r12's
// 64-block occupancy mistake). Ballot-built ordered token list with FREE
// range boundaries (b[j] = coff[8j]); thread t walks the ~N_TOK/KCLS matched
// rows accumulating dims {d0, d0+1} (coalesced ushort2), emitting bf16
// snapshots Sb at each range boundary + cnt_before (slice 0) + n2snap
// (LDS atomics -> one global atomic per (j,k) per block).
__global__ __launch_bounds__(256) void classscan_kernel(
    const unsigned short* __restrict__ xb, const int* __restrict__ lab,
    const float* __restrict__ avgs, unsigned short* __restrict__ Sb,
    float* __restrict__ n2snap, int* __restrict__ cnt_before) {
    __shared__ short list[N_TOK];              // 32 KB (worst case one class)
    __shared__ unsigned long long cmask[256];  // 2 KB: per-64-token-chunk masks
    __shared__ int coff[257];
    __shared__ int wt[4];
    __shared__ float n2l[JRANGES];

    int bid = blockIdx.x;
    int k = bid >> 2, s = bid & 3;
    int t = threadIdx.x, lane = t & 63, w = t >> 6;

    // pass 1: match mask per 64-token chunk (coalesced label reads + ballot)
    for (int i = 0; i < 64; i++) {
        int lb = lab[i * 256 + t];
        unsigned long long m = __ballot(lb == k);
        if (lane == 0) cmask[i * 4 + w] = m;
    }
    if (t < JRANGES) n2l[t] = 0.f;
    __syncthreads();

    // exclusive scan of the 256 chunk counts (thread t owns chunk t)
    int v = __popcll(cmask[t]);
    int p = v;
    for (int sh = 1; sh < 64; sh <<= 1) {
        int u = __shfl_up(p, sh, 64);
        if (lane >= sh) p += u;
    }
    if (lane == 63) wt[w] = p;
    __syncthreads();
    int woff = 0;
#pragma unroll
    for (int i = 0; i < 4; i++) if (i < w) woff += wt[i];
    coff[t] = woff + p - v;
    if (t == 255) coff[256] = woff + p;
    __syncthreads();

    // pass 2: ballot-rank scatter of ordered token indices
    for (int c = w; c < 256; c += 4) {
        unsigned long long m = cmask[c];
        if ((m >> lane) & 1ULL) {
            int rank = __popcll(m & ((1ULL << lane) - 1ULL));
            list[coff[c] + rank] = (short)((c >> 2) * 256 + (c & 3) * 64 + lane);
        }
    }
    __syncthreads();

    // prefix walk: thread owns dims {d0, d0+1}; range j = chunks 8j..8j+7
    int d0 = s * 512 + t * 2;
    float2 init, pref = {0.f, 0.f};
    {
        const float* ap = avgs + (size_t)k * DIM + d0;
        init.x = ap[0]; init.y = ap[1];
    }
    int i = 0;
#pragma unroll 1
    for (int j = 0; j < JRANGES; j++) {
        float2 snap = (i == 0) ? init : pref;
        *(ushort2*)&Sb[((size_t)j * KCLS + k) * DIM + d0] =
            make_ushort2(f2bf(snap.x), f2bf(snap.y));
        float pn = fmaf(snap.x, snap.x, snap.y * snap.y);
        pn = dpp_sum64(pn);
        if (lane == 63) atomicAdd(&n2l[j], pn);
        if (s == 0 && t == 0) cnt_before[j * KCLS + k] = i;
        int iend = coff[8 * (j + 1)];
#pragma unroll 1
        for (; i < iend; i++) {
            const unsigned short* r = xb + (size_t)list[i] * DIM + d0;
            ushort2 hv = *(const ushort2*)r;
            pref.x += bf2f(hv.x);
            pref.y += bf2f(hv.y);
        }
    }
    __syncthreads();
    if (t < JRANGES) atomicAdd(&n2snap[t * KCLS + k], n2l[t]);
}

// ---------------------------------------------------------------------------
// stage one bf16 panel K-chunk into LDS via global_load_lds (m173 pattern:
// linear LDS dest, XOR swizzle applied to the GLOBAL source address).
__device__ __forceinline__ void stage_panel(
    const unsigned short* __restrict__ src, short* dst, int nunits,
    int t, int kcoff) {
#pragma unroll
    for (int i = 0; i < 2; i++) {
        int u = t + 512 * i;
        if (u < nunits) {
            int row = u >> 3, gsw = u & 7;
            int g = gsw ^ (row & 7);
            const unsigned short* s = src + (size_t)row * DIM + kcoff + g * 8;
            __builtin_amdgcn_global_load_lds(
                (__attribute__((address_space(1))) void*)s,
                (__attribute__((address_space(3))) void*)(dst + u * 8),
                16, 0, 0);
        }
    }
}

// ---------------------------------------------------------------------------
// Kernel 3: per-range GEMMs via bf16 MFMA (round-17 version, best measured).
__global__ __launch_bounds__(512, 4) void gemm_kernel(
    const unsigned short* __restrict__ xb, const unsigned short* __restrict__ Sb,
    float* __restrict__ D0, unsigned short* __restrict__ Gbf) {
    __shared__ short PI[2][128 * KC];   // 2 x 16 KB (also reused as 128x128 TT)
    __shared__ short PJ[2][128 * KC];   // 2 x 16 KB
    static const char TIa[14] = {0,1,1,2,2,2,3,3,3,3, 0,1,2,3};
    static const char TJa[14] = {0,0,1,0,1,2,0,1,2,3, 0,0,0,0};

    int bid = blockIdx.x;
    int xcd = bid & 7;
    int q = bid >> 3;            // 0..55
    int j = xcd + 8 * (q / 14);  // range 0..31
    int tt = q % 14;
    int I = TIa[tt], J = TJa[tt];
    bool isD = (tt >= 10);
    bool diag = (!isD) && (I == J);
    int start = j * RANGE;
    int t = threadIdx.x, lane = t & 63, w = t >> 6;
    int rw = w & 3, cw = w >> 2;
    int NCF = isD ? 2 : 4;
    int colbase = isD ? cw * 32 : cw * 64;

    f32x4 acc[2][4];
#pragma unroll
    for (int a = 0; a < 2; a++)
#pragma unroll
        for (int b = 0; b < 4; b++) acc[a][b] = (f32x4){0.f, 0.f, 0.f, 0.f};

    const unsigned short* srcI = xb + (size_t)(start + I * 128) * DIM;
    const unsigned short* srcJ = isD ? (Sb + (size_t)(j * KCLS) * DIM)
                                     : (xb + (size_t)(start + J * 128) * DIM);
    int nJu = isD ? 512 : 1024;

    stage_panel(srcI, PI[0], 1024, t, 0);
    if (!diag) stage_panel(srcJ, PJ[0], nJu, t, 0);
    __syncthreads();

    for (int kc = 0; kc < DIM / KC; kc++) {   // 32 chunks
        int cur = kc & 1;
        if (kc + 1 < DIM / KC) {
            stage_panel(srcI, PI[cur ^ 1], 1024, t, (kc + 1) * KC);
            if (!diag) stage_panel(srcJ, PJ[cur ^ 1], nJu, t, (kc + 1) * KC);
        }
        const short* PA = PI[cur];
        const short* PB = diag ? PI[cur] : PJ[cur];
#pragma unroll
        for (int kk = 0; kk < 2; kk++) {
            int kb = kk * 32 + (lane >> 4) * 8;
            int ra = rw * 32 + (lane & 15);
            bf16x8 a0 = *(const bf16x8*)&PA[ra * KC + (kb ^ ((ra & 7) << 3))];
            int ra1 = ra + 16;
            bf16x8 a1 = *(const bf16x8*)&PA[ra1 * KC + (kb ^ ((ra1 & 7) << 3))];
#pragma unroll
            for (int f = 0; f < 4; f++) {
                if (f < NCF) {
                    int rb = colbase + f * 16 + (lane & 15);
                    bf16x8 bb = *(const bf16x8*)&PB[rb * KC + (kb ^ ((rb & 7) << 3))];
                    acc[0][f] = __builtin_amdgcn_mfma_f32_16x16x32_bf16(a0, bb, acc[0][f], 0, 0, 0);
                    acc[1][f] = __builtin_amdgcn_mfma_f32_16x16x32_bf16(a1, bb, acc[1][f], 0, 0, 0);
                }
            }
        }
        __syncthreads();
    }

    if (!isD) {
        size_t gbase = (size_t)j * (512 * 512);
        short* TT = &PI[0][0];  // 128x128 bf16 transpose buffer (32 KB)
#pragma unroll
        for (int rf = 0; rf < 2; rf++)
#pragma unroll
            for (int f = 0; f < 4; f++)
#pragma unroll
                for (int r = 0; r < 4; r++) {
                    int lr = rw * 32 + rf * 16 + (lane >> 4) * 4 + r;
                    int lc = colbase + f * 16 + (lane & 15);
                    unsigned short hv = f2bf(acc[rf][f][r]);
                    Gbf[gbase + (size_t)(I * 128 + lr) * 512 + J * 128 + lc] = hv;
                    if (I != J)  // swizzled LDS write for the transpose
                        TT[lc * 128 + (lr ^ ((lc & 15) << 3))] = (short)hv;
                }
        if (I != J) {
            __syncthreads();
#pragma unroll
            for (int i = 0; i < 4; i++) {  // coalesced transposed store
                int u = t + 512 * i;       // 2048 chunks of 8 bf16
                int tr = u >> 4, tc = u & 15;
                u16x8 v = *(const u16x8*)&TT[tr * 128 + ((tc * 8) ^ ((tr & 15) << 3))];
                *(u16x8*)&Gbf[gbase + (size_t)(J * 128 + tr) * 512 + I * 128 + tc * 8] = v;
            }
        }
    } else {
#pragma unroll
        for (int rf = 0; rf < 2; rf++)
#pragma unroll
            for (int f = 0; f < 2; f++)
#pragma unroll
                for (int r = 0; r < 4; r++) {
                    int grow = start + I * 128 + rw * 32 + rf * 16 + (lane >> 4) * 4 + r;
                    int gcol = colbase + f * 16 + (lane & 15);
                    D0[(size_t)grow * KCLS + gcol] = acc[rf][f][r];
                }
    }
}

// ---------------------------------------------------------------------------
// Kernel 4: parallel coalesced finalize (unchanged from round 16).
__global__ __launch_bounds__(512) void finalize_kernel(
    const int* __restrict__ lab, const float* __restrict__ D0,
    const unsigned short* __restrict__ Gbf, const float* __restrict__ vnorm2,
    const float* __restrict__ n2snap, const int* __restrict__ cnt_before,
    float* __restrict__ out) {
    __shared__ unsigned char lbl[RANGE];
    __shared__ short evl[RANGE];
    __shared__ short evcnt_s[8];
    __shared__ short evoff_s[9];
    __shared__ float corrb[8][RANGE];   // 16 KB
    __shared__ float cntb[8][RANGE];    // 16 KB
    __shared__ float rdv[RANGE];
    __shared__ float invna[RANGE + 8];
    __shared__ unsigned char vgs[8];

    int bid = blockIdx.x;
    int g = bid >> 5, jr = bid & 31;
    int g8 = g * 8;
    int start = jr * RANGE;
    int t = threadIdx.x, lane = t & 63, w = t >> 6;
    int c = g8 + w;

    lbl[t] = (unsigned char)lab[start + t];
    if (t < 8) vgs[t] = (cnt_before[jr * KCLS + g8 + t] == 0) ? 1 : 0;
    __syncthreads();

    // per-wave ordered event list for class c
    unsigned char myl[8];
    int cntL = 0;
#pragma unroll
    for (int i = 0; i < 8; i++) {
        myl[i] = lbl[lane * 8 + i];
        cntL += (myl[i] == c) ? 1 : 0;
    }
    int pre = cntL;
    for (int s = 1; s < 64; s <<= 1) {
        int v = __shfl_up(pre, s, 64);
        if (lane >= s) pre += v;
    }
    int tot = __shfl(pre, 63, 64);
    if (lane == 63) evcnt_s[w] = (short)tot;
    __syncthreads();
    if (t == 0) {
        int s = 0;
        for (int i = 0; i < 8; i++) { evoff_s[i] = (short)s; s += evcnt_s[i]; }
        evoff_s[8] = (short)s;
    }
    __syncthreads();
    int off = evoff_s[w], m = evcnt_s[w];
    {
        int wr = off + (pre - cntL);
#pragma unroll
        for (int i = 0; i < 8; i++)
            if (myl[i] == c) evl[wr++] = (short)(lane * 8 + i);
    }
    __syncthreads();

    // coalesced Gram-row broadcast accumulation
    const unsigned short* grb = Gbf + (size_t)jr * 262144;
    int vg = vgs[w];
#pragma unroll 1
    for (int chk = 0; chk < 8; chk++) {
        int tk = chk * 64 + lane;
        float corr = 0.f;
        int cnt = 0;
#pragma unroll 1
        for (int i = 0; i < m; i++) {
            int e = evl[off + i];
            float gv = bf2f(grb[(size_t)e * 512 + tk]);
            bool after = (tk > e);
            corr += after ? gv : 0.f;
            cnt += after ? 1 : 0;
        }
        corrb[w][tk] = corr;
        cntb[w][tk] = (float)cnt;
        if ((int)lbl[tk] == c) {
            float d0v = vg ? 0.f : D0[(size_t)(start + tk) * KCLS + c];
            rdv[off + cnt] = d0v + corr;
        }
    }
    __syncthreads();

    // n2 stage scan (8 scalar iterations per class)
    if (t < 8) {
        int o = evoff_s[t], mm = evcnt_s[t];
        int vgt = vgs[t];
        float n2 = n2snap[jr * KCLS + g8 + t];
        invna[o + t] = 1.0f / fmaxf(sqrtf(n2), EPS);
        for (int i = 1; i <= mm; i++) {
            int e = evl[o + i - 1];
            float xn2 = vnorm2[start + e];
            if (vgt && i == 1) n2 = xn2;
            else n2 += 2.f * rdv[o + i - 1] + xn2;
            invna[o + t + i] = 1.0f / fmaxf(sqrtf(n2), EPS);
        }
    }
    __syncthreads();

    // parallel output, thread t = token t
    {
        float4 d0a = *(const float4*)&D0[(size_t)(start + t) * KCLS + g8];
        float4 d0b = *(const float4*)&D0[(size_t)(start + t) * KCLS + g8 + 4];
        float d0[8] = {d0a.x, d0a.y, d0a.z, d0a.w, d0b.x, d0b.y, d0b.z, d0b.w};
        float nvinv = 1.0f / fmaxf(sqrtf(vnorm2[start + t]), EPS);
        float o8[8];
#pragma unroll
        for (int cc = 0; cc < 8; cc++) {
            float corr = corrb[cc][t];
            int cnt = (int)cntb[cc][t];
            float dot = (vgs[cc] && cnt > 0) ? corr : (d0[cc] + corr);
            o8[cc] = dot * invna[evoff_s[cc] + cc + cnt] * nvinv;
        }
        float4 oa = {o8[0], o8[1], o8[2], o8[3]};
        float4 ob = {o8[4], o8[5], o8[6], o8[7]};
        float* op = &out[(size_t)(start + t) * KCLS + g8];
        *(float4*)op = oa;
        *(float4*)(op + 4) = ob;
    }
}

// ---------------------------------------------------------------------------
extern "C" void kernel_launch(void* const* d_in, const int* in_sizes, int n_in,
                              void* d_out, int out_size, void* d_ws, size_t ws_size,
                              hipStream_t stream) {
    const float* inputs = (const float*)d_in[0];
    const float* class_avgs = (const float*)d_in[1];
    const int* labels_raw = (const int*)d_in[2];
    float* out = (float*)d_out;
    char* ws = (char*)d_ws;

    size_t off = 0;
    int* lab = (int*)(ws + off);          off += (size_t)N_TOK * 4;
    int* cnt_before = (int*)(ws + off);   off += (size_t)JRANGES * KCLS * 4;
    float* n2snap = (float*)(ws + off);   off += (size_t)JRANGES * KCLS * 4;
    float* vnorm2 = (float*)(ws + off);   off += (size_t)N_TOK * 4;
    off = (off + 255) & ~(size_t)255;
    unsigned short* Xb = (unsigned short*)(ws + off);
    off += (size_t)N_TOK * DIM * 2;                                   // 64 MB
    unsigned short* Sb = (unsigned short*)(ws + off);
    off += (size_t)JRANGES * KCLS * DIM * 2;                          // 8 MB
    float* D0 = (float*)(ws + off);       off += (size_t)N_TOK * KCLS * 4;  // 4 MB
    unsigned short* Gbf = (unsigned short*)(ws + off);
    off += (size_t)JRANGES * 512 * 512 * 2;                           // 16 MB

    prep_kernel<<<N_TOK / 4, 256, 0, stream>>>(inputs, Xb, vnorm2, labels_raw,
                                               lab, n2snap);
    classscan_kernel<<<KCLS * 4, 256, 0, stream>>>(Xb, lab, class_avgs, Sb,
                                                   n2snap, cnt_before);
    gemm_kernel<<<14 * JRANGES, 512, 0, stream>>>(Xb, Sb, D0, Gbf);
    finalize_kernel<<<8 * JRANGES, 512, 0, stream>>>(lab, D0, Gbf, vnorm2, n2snap,
                                                     cnt_before, out);
}

// Round 20
// 153.075 us; speedup vs baseline: 1.5207x; 1.5207x over previous
//
#include <hip/hip_runtime.h>
#include <hip/hip_bf16.h>

#define N_TOK 16384
#define DIM 2048
#define KCLS 64
#define JRANGES 32
#define RANGE 512   // N_TOK / JRANGES
#define KC 64       // GEMM K-chunk (bf16, double-buffered)
#define EPS 1e-8f

typedef short bf16x8 __attribute__((ext_vector_type(8)));
typedef unsigned short u16x8 __attribute__((ext_vector_type(8)));
typedef float f32x4 __attribute__((ext_vector_type(4)));

__device__ __forceinline__ unsigned short f2bf(float f) {
    unsigned u = __float_as_uint(f);
    u += 0x7fffu + ((u >> 16) & 1u);
    return (unsigned short)(u >> 16);
}
__device__ __forceinline__ float bf2f(unsigned short s) {
    return __uint_as_float(((unsigned)s) << 16);
}

__device__ __forceinline__ float dpp_sum64(float x) {
    x += __int_as_float(__builtin_amdgcn_update_dpp(0, __float_as_int(x), 0x111, 0xf, 0xf, true));
    x += __int_as_float(__builtin_amdgcn_update_dpp(0, __float_as_int(x), 0x112, 0xf, 0xf, true));
    x += __int_as_float(__builtin_amdgcn_update_dpp(0, __float_as_int(x), 0x114, 0xf, 0xf, true));
    x += __int_as_float(__builtin_amdgcn_update_dpp(0, __float_as_int(x), 0x118, 0xf, 0xf, true));
    x += __int_as_float(__builtin_amdgcn_update_dpp(0, __float_as_int(x), 0x142, 0xf, 0xf, true));
    x += __int_as_float(__builtin_amdgcn_update_dpp(0, __float_as_int(x), 0x143, 0xf, 0xf, true));
    return x;  // valid in lane 63 only
}

// ---------------------------------------------------------------------------
// Kernel 1: prep — cast X to bf16 + exact fp32 token norms.
// Fused: blocks 0..63 normalize the labels chunk (int64/int32 sniff);
// blocks 64..71 zero n2snap (scan accumulates into it atomically).
__global__ __launch_bounds__(256) void prep_kernel(
    const float* __restrict__ x, unsigned short* __restrict__ xb,
    float* __restrict__ vnorm2, const int* __restrict__ raw,
    int* __restrict__ lab, float* __restrict__ n2snap) {
    int bid = blockIdx.x, tid = threadIdx.x;
    if (bid < 64) {  // label duty (block-uniform branch)
        __shared__ int not64;
        if (tid == 0) not64 = 0;
        __syncthreads();
        int n0 = bid * 256 + tid;
        int lo = raw[2 * n0], hi = raw[2 * n0 + 1];
        if (hi != 0 || lo < 0 || lo >= KCLS) atomicOr(&not64, 1);
        __syncthreads();
        lab[n0] = not64 ? raw[n0] : raw[2 * n0];
    } else if (bid < 72) {
        n2snap[(bid - 64) * 256 + tid] = 0.f;
    }
    int w4 = tid >> 6, lane = tid & 63;
    int n = bid * 4 + w4;
    const float* v = x + (size_t)n * DIM;
    unsigned short* o = xb + (size_t)n * DIM;
    float p = 0.f;
#pragma unroll
    for (int it = 0; it < 8; it++) {
        float4 a = *(const float4*)(v + it * 256 + lane * 4);
        p = fmaf(a.x, a.x, p); p = fmaf(a.y, a.y, p);
        p = fmaf(a.z, a.z, p); p = fmaf(a.w, a.w, p);
        ushort4 h = make_ushort4(f2bf(a.x), f2bf(a.y), f2bf(a.z), f2bf(a.w));
        *(ushort4*)(o + it * 256 + lane * 4) = h;
    }
    p = dpp_sum64(p);
    if (lane == 63) vnorm2[n] = p;
}

// ---------------------------------------------------------------------------
// Kernel 2: per-(range, class) partial sum of class-k token vectors (bf16 in,
// fp32 accum). bid = k*32 + j -> bid%8 == j%8 (XCD locality). Ordered match
// list built via wave-prefix-scan.
__global__ __launch_bounds__(256) void partials_kernel(
    const unsigned short* __restrict__ xb, const int* __restrict__ lab,
    float* __restrict__ spart, int* __restrict__ cnt_range) {
    __shared__ unsigned char ll[RANGE];
    __shared__ short ml[RANGE];
    __shared__ int wt[4];

    int bid = blockIdx.x;
    int j = bid & 31, k = bid >> 5;
    int t = threadIdx.x, lane = t & 63, w = t >> 6;

    // labels + parallel ordered match list (thread t covers tokens 2t, 2t+1)
    int2 lp = *(const int2*)(lab + j * RANGE + 2 * t);
    ll[2 * t] = (unsigned char)lp.x;
    ll[2 * t + 1] = (unsigned char)lp.y;
    int m0 = (lp.x == k) ? 1 : 0;
    int m1 = (lp.y == k) ? 1 : 0;
    int cnt = m0 + m1;
    int pre = cnt;
    for (int s = 1; s < 64; s <<= 1) {
        int v = __shfl_up(pre, s, 64);
        if (lane >= s) pre += v;
    }
    if (lane == 63) wt[w] = pre;
    __syncthreads();
    int woff = 0, nm = 0;
#pragma unroll
    for (int i = 0; i < 4; i++) { if (i < w) woff += wt[i]; nm += wt[i]; }
    {
        int wr = woff + pre - cnt;
        if (m0) ml[wr++] = (short)(2 * t);
        if (m1) ml[wr] = (short)(2 * t + 1);
    }
    __syncthreads();
    if (t == 0) cnt_range[j * KCLS + k] = nm;

    // fp32 accumulate of the nm bf16 rows; thread owns dims 8t..8t+7
    float acc[8] = {0, 0, 0, 0, 0, 0, 0, 0};
    for (int m = 0; m < nm; m++) {
        const unsigned short* r = xb + (size_t)(j * RANGE + (int)ml[m]) * DIM + t * 8;
        u16x8 hv = *(const u16x8*)r;
#pragma unroll
        for (int i = 0; i < 8; i++) acc[i] += bf2f(hv[i]);
    }
    float* dst = spart + ((size_t)j * KCLS + k) * DIM + t * 8;
    *(float4*)dst = make_float4(acc[0], acc[1], acc[2], acc[3]);
    *(float4*)(dst + 4) = make_float4(acc[4], acc[5], acc[6], acc[7]);
}

// ---------------------------------------------------------------------------
// Kernel 3: in-place exclusive scan over ranges -> boundary snapshots;
// emits bf16 mirror Sb AND accumulates ||snapshot||^2 into n2snap
// (per-wave DPP reduce + one atomicAdd per wave).
__global__ __launch_bounds__(256) void scan_kernel(
    const float* __restrict__ avgs, float* __restrict__ spart,
    unsigned short* __restrict__ Sb, float* __restrict__ n2snap,
    const int* __restrict__ cnt_range, int* __restrict__ cnt_before) {
    int t = blockIdx.x * 256 + threadIdx.x;  // 32768 threads
    int lane = threadIdx.x & 63;
    int k = t >> 9;
    int d4 = t & 511;
    int d = d4 * 4;
    float4 run = {0, 0, 0, 0};
    int cb = 0;
    float4 init = *(const float4*)(avgs + (size_t)k * DIM + d);
    for (int j = 0; j < JRANGES; j++) {
        size_t idx = ((size_t)j * KCLS + k) * DIM + d;
        float4 part = *(const float4*)(spart + idx);
        float4 w = (cb == 0) ? init : run;
        *(ushort4*)(Sb + idx) = make_ushort4(f2bf(w.x), f2bf(w.y), f2bf(w.z), f2bf(w.w));
        float s = 0.f;
        s = fmaf(w.x, w.x, s); s = fmaf(w.y, w.y, s);
        s = fmaf(w.z, w.z, s); s = fmaf(w.w, w.w, s);
        s = dpp_sum64(s);
        if (lane == 63) atomicAdd(&n2snap[j * KCLS + k], s);
        if (d4 == 0) cnt_before[j * KCLS + k] = cb;
        run.x += part.x; run.y += part.y; run.z += part.z; run.w += part.w;
        cb += cnt_range[j * KCLS + k];
    }
}

// ---------------------------------------------------------------------------
// stage one bf16 panel K-chunk into LDS via global_load_lds (m173 pattern:
// linear LDS dest, XOR swizzle applied to the GLOBAL source address).
__device__ __forceinline__ void stage_panel(
    const unsigned short* __restrict__ src, short* dst, int nunits,
    int t, int kcoff) {
#pragma unroll
    for (int i = 0; i < 2; i++) {
        int u = t + 512 * i;
        if (u < nunits) {
            int row = u >> 3, gsw = u & 7;
            int g = gsw ^ (row & 7);
            const unsigned short* s = src + (size_t)row * DIM + kcoff + g * 8;
            __builtin_amdgcn_global_load_lds(
                (__attribute__((address_space(1))) void*)s,
                (__attribute__((address_space(3))) void*)(dst + u * 8),
                16, 0, 0);
        }
    }
}

// ---------------------------------------------------------------------------
// Kernel 4: per-range GEMMs via bf16 MFMA, double-buffered global_load_lds
// staging (KC=64). tt 0..9: G-tiles (I>=J, 128x128) of G = X·X^T;
// tt 10..13: D-tiles (128 tokens x 64 classes) of D0 = X·S^T.
// XCD-sequential range scheduling (r17 best-measured).
__global__ __launch_bounds__(512, 4) void gemm_kernel(
    const unsigned short* __restrict__ xb, const unsigned short* __restrict__ Sb,
    float* __restrict__ D0, unsigned short* __restrict__ Gbf) {
    __shared__ short PI[2][128 * KC];   // 2 x 16 KB (also reused as 128x128 TT)
    __shared__ short PJ[2][128 * KC];   // 2 x 16 KB
    static const char TIa[14] = {0,1,1,2,2,2,3,3,3,3, 0,1,2,3};
    static const char TJa[14] = {0,0,1,0,1,2,0,1,2,3, 0,0,0,0};

    int bid = blockIdx.x;
    int xcd = bid & 7;
    int q = bid >> 3;            // 0..55
    int j = xcd + 8 * (q / 14);  // range 0..31
    int tt = q % 14;
    int I = TIa[tt], J = TJa[tt];
    bool isD = (tt >= 10);
    bool diag = (!isD) && (I == J);
    int start = j * RANGE;
    int t = threadIdx.x, lane = t & 63, w = t >> 6;
    int rw = w & 3, cw = w >> 2;
    int NCF = isD ? 2 : 4;
    int colbase = isD ? cw * 32 : cw * 64;

    f32x4 acc[2][4];
#pragma unroll
    for (int a = 0; a < 2; a++)
#pragma unroll
        for (int b = 0; b < 4; b++) acc[a][b] = (f32x4){0.f, 0.f, 0.f, 0.f};

    const unsigned short* srcI = xb + (size_t)(start + I * 128) * DIM;
    const unsigned short* srcJ = isD ? (Sb + (size_t)(j * KCLS) * DIM)
                                     : (xb + (size_t)(start + J * 128) * DIM);
    int nJu = isD ? 512 : 1024;

    stage_panel(srcI, PI[0], 1024, t, 0);
    if (!diag) stage_panel(srcJ, PJ[0], nJu, t, 0);
    __syncthreads();

    for (int kc = 0; kc < DIM / KC; kc++) {   // 32 chunks
        int cur = kc & 1;
        if (kc + 1 < DIM / KC) {
            stage_panel(srcI, PI[cur ^ 1], 1024, t, (kc + 1) * KC);
            if (!diag) stage_panel(srcJ, PJ[cur ^ 1], nJu, t, (kc + 1) * KC);
        }
        const short* PA = PI[cur];
        const short* PB = diag ? PI[cur] : PJ[cur];
#pragma unroll
        for (int kk = 0; kk < 2; kk++) {
            int kb = kk * 32 + (lane >> 4) * 8;
            int ra = rw * 32 + (lane & 15);
            bf16x8 a0 = *(const bf16x8*)&PA[ra * KC + (kb ^ ((ra & 7) << 3))];
            int ra1 = ra + 16;
            bf16x8 a1 = *(const bf16x8*)&PA[ra1 * KC + (kb ^ ((ra1 & 7) << 3))];
#pragma unroll
            for (int f = 0; f < 4; f++) {
                if (f < NCF) {
                    int rb = colbase + f * 16 + (lane & 15);
                    bf16x8 bb = *(const bf16x8*)&PB[rb * KC + (kb ^ ((rb & 7) << 3))];
                    acc[0][f] = __builtin_amdgcn_mfma_f32_16x16x32_bf16(a0, bb, acc[0][f], 0, 0, 0);
                    acc[1][f] = __builtin_amdgcn_mfma_f32_16x16x32_bf16(a1, bb, acc[1][f], 0, 0, 0);
                }
            }
        }
        __syncthreads();
    }

    if (!isD) {
        size_t gbase = (size_t)j * (512 * 512);
        short* TT = &PI[0][0];  // 128x128 bf16 transpose buffer (32 KB)
#pragma unroll
        for (int rf = 0; rf < 2; rf++)
#pragma unroll
            for (int f = 0; f < 4; f++)
#pragma unroll
                for (int r = 0; r < 4; r++) {
                    int lr = rw * 32 + rf * 16 + (lane >> 4) * 4 + r;
                    int lc = colbase + f * 16 + (lane & 15);
                    unsigned short hv = f2bf(acc[rf][f][r]);
                    Gbf[gbase + (size_t)(I * 128 + lr) * 512 + J * 128 + lc] = hv;
                    if (I != J)  // swizzled LDS write for the transpose
                        TT[lc * 128 + (lr ^ ((lc & 15) << 3))] = (short)hv;
                }
        if (I != J) {
            __syncthreads();
#pragma unroll
            for (int i = 0; i < 4; i++) {  // coalesced transposed store
                int u = t + 512 * i;       // 2048 chunks of 8 bf16
                int tr = u >> 4, tc = u & 15;
                u16x8 v = *(const u16x8*)&TT[tr * 128 + ((tc * 8) ^ ((tr & 15) << 3))];
                *(u16x8*)&Gbf[gbase + (size_t)(J * 128 + tr) * 512 + I * 128 + tc * 8] = v;
            }
        }
    } else {
#pragma unroll
        for (int rf = 0; rf < 2; rf++)
#pragma unroll
            for (int f = 0; f < 2; f++)
#pragma unroll
                for (int r = 0; r < 4; r++) {
                    int grow = start + I * 128 + rw * 32 + rf * 16 + (lane >> 4) * 4 + r;
                    int gcol = colbase + f * 16 + (lane & 15);
                    D0[(size_t)grow * KCLS + gcol] = acc[rf][f][r];
                }
    }
}

// ---------------------------------------------------------------------------
// Kernel 5: parallel coalesced finalize (unchanged from round 16).
__global__ __launch_bounds__(512) void finalize_kernel(
    const int* __restrict__ lab, const float* __restrict__ D0,
    const unsigned short* __restrict__ Gbf, const float* __restrict__ vnorm2,
    const float* __restrict__ n2snap, const int* __restrict__ cnt_before,
    float* __restrict__ out) {
    __shared__ unsigned char lbl[RANGE];
    __shared__ short evl[RANGE];
    __shared__ short evcnt_s[8];
    __shared__ short evoff_s[9];
    __shared__ float corrb[8][RANGE];   // 16 KB
    __shared__ float cntb[8][RANGE];    // 16 KB
    __shared__ float rdv[RANGE];
    __shared__ float invna[RANGE + 8];
    __shared__ unsigned char vgs[8];

    int bid = blockIdx.x;
    int g = bid >> 5, jr = bid & 31;
    int g8 = g * 8;
    int start = jr * RANGE;
    int t = threadIdx.x, lane = t & 63, w = t >> 6;
    int c = g8 + w;

    lbl[t] = (unsigned char)lab[start + t];
    if (t < 8) vgs[t] = (cnt_before[jr * KCLS + g8 + t] == 0) ? 1 : 0;
    __syncthreads();

    // per-wave ordered event list for class c
    unsigned char myl[8];
    int cntL = 0;
#pragma unroll
    for (int i = 0; i < 8; i++) {
        myl[i] = lbl[lane * 8 + i];
        cntL += (myl[i] == c) ? 1 : 0;
    }
    int pre = cntL;
    for (int s = 1; s < 64; s <<= 1) {
        int v = __shfl_up(pre, s, 64);
        if (lane >= s) pre += v;
    }
    int tot = __shfl(pre, 63, 64);
    if (lane == 63) evcnt_s[w] = (short)tot;
    __syncthreads();
    if (t == 0) {
        int s = 0;
        for (int i = 0; i < 8; i++) { evoff_s[i] = (short)s; s += evcnt_s[i]; }
        evoff_s[8] = (short)s;
    }
    __syncthreads();
    int off = evoff_s[w], m = evcnt_s[w];
    {
        int wr = off + (pre - cntL);
#pragma unroll
        for (int i = 0; i < 8; i++)
            if (myl[i] == c) evl[wr++] = (short)(lane * 8 + i);
    }
    __syncthreads();

    // coalesced Gram-row broadcast accumulation
    const unsigned short* grb = Gbf + (size_t)jr * 262144;
    int vg = vgs[w];
#pragma unroll 1
    for (int chk = 0; chk < 8; chk++) {
        int tk = chk * 64 + lane;
        float corr = 0.f;
        int cnt = 0;
#pragma unroll 1
        for (int i = 0; i < m; i++) {
            int e = evl[off + i];
            float gv = bf2f(grb[(size_t)e * 512 + tk]);
            bool after = (tk > e);
            corr += after ? gv : 0.f;
            cnt += after ? 1 : 0;
        }
        corrb[w][tk] = corr;
        cntb[w][tk] = (float)cnt;
        if ((int)lbl[tk] == c) {
            float d0v = vg ? 0.f : D0[(size_t)(start + tk) * KCLS + c];
            rdv[off + cnt] = d0v + corr;
        }
    }
    __syncthreads();

    // n2 stage scan (8 scalar iterations per class)
    if (t < 8) {
        int o = evoff_s[t], mm = evcnt_s[t];
        int vgt = vgs[t];
        float n2 = n2snap[jr * KCLS + g8 + t];
        invna[o + t] = 1.0f / fmaxf(sqrtf(n2), EPS);
        for (int i = 1; i <= mm; i++) {
            int e = evl[o + i - 1];
            float xn2 = vnorm2[start + e];
            if (vgt && i == 1) n2 = xn2;
            else n2 += 2.f * rdv[o + i - 1] + xn2;
            invna[o + t + i] = 1.0f / fmaxf(sqrtf(n2), EPS);
        }
    }
    __syncthreads();

    // parallel output, thread t = token t
    {
        float4 d0a = *(const float4*)&D0[(size_t)(start + t) * KCLS + g8];
        float4 d0b = *(const float4*)&D0[(size_t)(start + t) * KCLS + g8 + 4];
        float d0[8] = {d0a.x, d0a.y, d0a.z, d0a.w, d0b.x, d0b.y, d0b.z, d0b.w};
        float nvinv = 1.0f / fmaxf(sqrtf(vnorm2[start + t]), EPS);
        float o8[8];
#pragma unroll
        for (int cc = 0; cc < 8; cc++) {
            float corr = corrb[cc][t];
            int cnt = (int)cntb[cc][t];
            float dot = (vgs[cc] && cnt > 0) ? corr : (d0[cc] + corr);
            o8[cc] = dot * invna[evoff_s[cc] + cc + cnt] * nvinv;
        }
        float4 oa = {o8[0], o8[1], o8[2], o8[3]};
        float4 ob = {o8[4], o8[5], o8[6], o8[7]};
        float* op = &out[(size_t)(start + t) * KCLS + g8];
        *(float4*)op = oa;
        *(float4*)(op + 4) = ob;
    }
}

// ---------------------------------------------------------------------------
extern "C" void kernel_launch(void* const* d_in, const int* in_sizes, int n_in,
                              void* d_out, int out_size, void* d_ws, size_t ws_size,
                              hipStream_t stream) {
    const float* inputs = (const float*)d_in[0];
    const float* class_avgs = (const float*)d_in[1];
    const int* labels_raw = (const int*)d_in[2];
    float* out = (float*)d_out;
    char* ws = (char*)d_ws;

    size_t off = 0;
    int* lab = (int*)(ws + off);          off += (size_t)N_TOK * 4;
    int* cnt_range = (int*)(ws + off);    off += (size_t)JRANGES * KCLS * 4;
    int* cnt_before = (int*)(ws + off);   off += (size_t)JRANGES * KCLS * 4;
    float* n2snap = (float*)(ws + off);   off += (size_t)JRANGES * KCLS * 4;
    float* vnorm2 = (float*)(ws + off);   off += (size_t)N_TOK * 4;
    off = (off + 255) & ~(size_t)255;
    unsigned short* Xb = (unsigned short*)(ws + off);
    off += (size_t)N_TOK * DIM * 2;                                   // 64 MB
    unsigned short* Sb = (unsigned short*)(ws + off);
    off += (size_t)JRANGES * KCLS * DIM * 2;                          // 8 MB
    float* D0 = (float*)(ws + off);       off += (size_t)N_TOK * KCLS * 4;  // 4 MB
    unsigned short* Gbf = (unsigned short*)(ws + off);
    off += (size_t)JRANGES * 512 * 512 * 2;                           // 16 MB
    float* spart = (float*)(ws + off);    off += (size_t)JRANGES * KCLS * DIM * 4;  // 16 MB

    prep_kernel<<<N_TOK / 4, 256, 0, stream>>>(inputs, Xb, vnorm2, labels_raw,
                                               lab, n2snap);
    partials_kernel<<<JRANGES * KCLS, 256, 0, stream>>>(Xb, lab, spart, cnt_range);
    scan_kernel<<<(KCLS * (DIM / 4)) / 256, 256, 0, stream>>>(class_avgs, spart, Sb,
                                                              n2snap, cnt_range,
                                                              cnt_before);
    gemm_kernel<<<14 * JRANGES, 512, 0, stream>>>(Xb, Sb, D0, Gbf);
    finalize_kernel<<<8 * JRANGES, 512, 0, stream>>>(lab, D0, Gbf, vnorm2, n2snap,
                                                     cnt_before, out);
}